// Round 1
// baseline (3283.229 us; speedup 1.0000x reference)
//
#include <hip/hip_runtime.h>

#define NNODES 50000
#define NEDGES 800000
// dims: N_IN=64, E_IN=32, N_OUT=64, E_OUT=32
// msg:  [96 -> 64], node: [128 -> 64], edge: [160 -> 32]

// tanh(x) = 1 - 2/(exp(2x)+1); exp->inf gives 1, exp->0 gives -1. No NaN.
__device__ __forceinline__ float fast_tanh(float x) {
    float e = __expf(2.0f * x);
    return 1.0f - 2.0f * __builtin_amdgcn_rcpf(e + 1.0f);
}

// acc[j] += xk * wrow[j], wrow is wave-uniform LDS row (ds_read_b128 broadcast)
template <int NOUT>
__device__ __forceinline__ void fma_row(float (&acc)[NOUT], float xk,
                                        const float* __restrict__ wrow) {
#pragma unroll
    for (int j4 = 0; j4 < NOUT / 4; ++j4) {
        float4 w4 = ((const float4*)wrow)[j4];
        acc[j4 * 4 + 0] = fmaf(xk, w4.x, acc[j4 * 4 + 0]);
        acc[j4 * 4 + 1] = fmaf(xk, w4.y, acc[j4 * 4 + 1]);
        acc[j4 * 4 + 2] = fmaf(xk, w4.z, acc[j4 * 4 + 2]);
        acc[j4 * 4 + 3] = fmaf(xk, w4.w, acc[j4 * 4 + 3]);
    }
}

template <int NOUT>
__device__ __forceinline__ void fma_quad(float (&acc)[NOUT], float4 x4,
                                         const float* __restrict__ wbase) {
    fma_row<NOUT>(acc, x4.x, wbase + 0 * NOUT);
    fma_row<NOUT>(acc, x4.y, wbase + 1 * NOUT);
    fma_row<NOUT>(acc, x4.z, wbase + 2 * NOUT);
    fma_row<NOUT>(acc, x4.w, wbase + 3 * NOUT);
}

// ---------------- kernel 1: message MLP + scatter add ----------------
// thread = edge. m = tanh([feat[src], edge_feat] @ w_msg + b_msg)
// atomicAdd into sums[dst] (= d_out h region) and cnt[dst].
__global__ __launch_bounds__(256, 4) void msg_scatter(
    const float* __restrict__ feat, const float* __restrict__ edge_feat,
    const float* __restrict__ w_msg, const float* __restrict__ b_msg,
    const int* __restrict__ src_idx, const int* __restrict__ dst_idx,
    float* __restrict__ sums, float* __restrict__ cnt) {
    __shared__ __align__(16) float wl[96 * 64];  // 24.6 KB
    __shared__ __align__(16) float bl[64];
    for (int i = threadIdx.x; i < 96 * 64; i += 256) wl[i] = w_msg[i];
    if (threadIdx.x < 64) bl[threadIdx.x] = b_msg[threadIdx.x];
    __syncthreads();

    const int t = blockIdx.x * 256 + threadIdx.x;  // 3125*256 == 800000 exactly
    const int src = src_idx[t];
    const int dst = dst_idx[t];

    float acc[64];
#pragma unroll
    for (int j4 = 0; j4 < 16; ++j4) {
        float4 b4 = ((const float4*)bl)[j4];
        acc[j4 * 4 + 0] = b4.x; acc[j4 * 4 + 1] = b4.y;
        acc[j4 * 4 + 2] = b4.z; acc[j4 * 4 + 3] = b4.w;
    }

    const float4* fa = (const float4*)(feat + (size_t)src * 64);
    const float4* fe = (const float4*)(edge_feat + (size_t)t * 32);

#pragma unroll 1
    for (int kq = 0; kq < 16; ++kq)  // src_h rows 0..63
        fma_quad<64>(acc, fa[kq], &wl[(kq * 4) * 64]);
#pragma unroll 1
    for (int kq = 0; kq < 8; ++kq)   // edge_feat rows 64..95
        fma_quad<64>(acc, fe[kq], &wl[(64 + kq * 4) * 64]);

    float* srow = sums + (size_t)dst * 64;
#pragma unroll 1
    for (int j = 0; j < 64; ++j)
        atomicAdd(&srow[j], fast_tanh(acc[j]));
    atomicAdd(&cnt[dst], 1.0f);
}

// ---------------- kernel 2: node MLP ----------------
// thread = node. h = tanh([sums/max(cnt,1), feat] @ w_node + b_node)
// reads sums from h buffer, overwrites with h (own row only -> safe).
__global__ __launch_bounds__(256, 4) void node_update(
    const float* __restrict__ feat,
    const float* __restrict__ w_node, const float* __restrict__ b_node,
    const float* __restrict__ cnt, float* __restrict__ h) {
    __shared__ __align__(16) float wl[128 * 64];  // 32 KB
    __shared__ __align__(16) float bl[64];
    for (int i = threadIdx.x; i < 128 * 64; i += 256) wl[i] = w_node[i];
    if (threadIdx.x < 64) bl[threadIdx.x] = b_node[threadIdx.x];
    __syncthreads();

    const int t = blockIdx.x * 256 + threadIdx.x;
    if (t >= NNODES) return;

    const float inv = __builtin_amdgcn_rcpf(fmaxf(cnt[t], 1.0f));

    float acc[64];
#pragma unroll
    for (int j4 = 0; j4 < 16; ++j4) {
        float4 b4 = ((const float4*)bl)[j4];
        acc[j4 * 4 + 0] = b4.x; acc[j4 * 4 + 1] = b4.y;
        acc[j4 * 4 + 2] = b4.z; acc[j4 * 4 + 3] = b4.w;
    }

    const float4* sv = (const float4*)(h + (size_t)t * 64);
    const float4* fv = (const float4*)(feat + (size_t)t * 64);

#pragma unroll 1
    for (int kq = 0; kq < 16; ++kq) {  // neigh rows 0..63
        float4 x4 = sv[kq];
        x4.x *= inv; x4.y *= inv; x4.z *= inv; x4.w *= inv;
        fma_quad<64>(acc, x4, &wl[(kq * 4) * 64]);
    }
#pragma unroll 1
    for (int kq = 0; kq < 16; ++kq)    // feat rows 64..127
        fma_quad<64>(acc, fv[kq], &wl[(64 + kq * 4) * 64]);

    float4* ho = (float4*)(h + (size_t)t * 64);
#pragma unroll 1
    for (int j4 = 0; j4 < 16; ++j4) {
        float4 o;
        o.x = fast_tanh(acc[j4 * 4 + 0]);
        o.y = fast_tanh(acc[j4 * 4 + 1]);
        o.z = fast_tanh(acc[j4 * 4 + 2]);
        o.w = fast_tanh(acc[j4 * 4 + 3]);
        ho[j4] = o;
    }
}

// ---------------- kernel 3: edge MLP ----------------
// thread = edge. e = tanh([feat[src], h[dst], edge_feat] @ w_edge + b_edge)
__global__ __launch_bounds__(256, 4) void edge_update(
    const float* __restrict__ feat, const float* __restrict__ edge_feat,
    const float* __restrict__ h,
    const float* __restrict__ w_edge, const float* __restrict__ b_edge,
    const int* __restrict__ src_idx, const int* __restrict__ dst_idx,
    float* __restrict__ e_out) {
    __shared__ __align__(16) float wl[160 * 32];  // 20 KB
    __shared__ __align__(16) float bl[32];
    for (int i = threadIdx.x; i < 160 * 32; i += 256) wl[i] = w_edge[i];
    if (threadIdx.x < 32) bl[threadIdx.x] = b_edge[threadIdx.x];
    __syncthreads();

    const int t = blockIdx.x * 256 + threadIdx.x;  // exact multiple
    const int src = src_idx[t];
    const int dst = dst_idx[t];

    float acc[32];
#pragma unroll
    for (int j4 = 0; j4 < 8; ++j4) {
        float4 b4 = ((const float4*)bl)[j4];
        acc[j4 * 4 + 0] = b4.x; acc[j4 * 4 + 1] = b4.y;
        acc[j4 * 4 + 2] = b4.z; acc[j4 * 4 + 3] = b4.w;
    }

    const float4* fa = (const float4*)(feat + (size_t)src * 64);
    const float4* fh = (const float4*)(h + (size_t)dst * 64);
    const float4* fe = (const float4*)(edge_feat + (size_t)t * 32);

#pragma unroll 1
    for (int kq = 0; kq < 16; ++kq)  // src_h rows 0..63
        fma_quad<32>(acc, fa[kq], &wl[(kq * 4) * 32]);
#pragma unroll 1
    for (int kq = 0; kq < 16; ++kq)  // h[dst] rows 64..127
        fma_quad<32>(acc, fh[kq], &wl[(64 + kq * 4) * 32]);
#pragma unroll 1
    for (int kq = 0; kq < 8; ++kq)   // edge_feat rows 128..159
        fma_quad<32>(acc, fe[kq], &wl[(128 + kq * 4) * 32]);

    float4* eo = (float4*)(e_out + (size_t)t * 32);
#pragma unroll 1
    for (int j4 = 0; j4 < 8; ++j4) {
        float4 o;
        o.x = fast_tanh(acc[j4 * 4 + 0]);
        o.y = fast_tanh(acc[j4 * 4 + 1]);
        o.z = fast_tanh(acc[j4 * 4 + 2]);
        o.w = fast_tanh(acc[j4 * 4 + 3]);
        eo[j4] = o;
    }
}

extern "C" void kernel_launch(void* const* d_in, const int* in_sizes, int n_in,
                              void* d_out, int out_size, void* d_ws, size_t ws_size,
                              hipStream_t stream) {
    const float* feat      = (const float*)d_in[0];
    const float* edge_feat = (const float*)d_in[1];
    const float* w_msg     = (const float*)d_in[2];
    const float* b_msg     = (const float*)d_in[3];
    const float* w_node    = (const float*)d_in[4];
    const float* b_node    = (const float*)d_in[5];
    const float* w_edge    = (const float*)d_in[6];
    const float* b_edge    = (const float*)d_in[7];
    const int*   src_idx   = (const int*)d_in[8];
    const int*   dst_idx   = (const int*)d_in[9];

    float* h = (float*)d_out;                         // [50000,64]; doubles as sums
    float* e = (float*)d_out + (size_t)NNODES * 64;   // [800000,32]
    float* cnt = (float*)d_ws;                        // [50000]

    hipMemsetAsync(h, 0, (size_t)NNODES * 64 * sizeof(float), stream);
    hipMemsetAsync(cnt, 0, (size_t)NNODES * sizeof(float), stream);

    msg_scatter<<<NEDGES / 256, 256, 0, stream>>>(feat, edge_feat, w_msg, b_msg,
                                                  src_idx, dst_idx, h, cnt);
    node_update<<<(NNODES + 255) / 256, 256, 0, stream>>>(feat, w_node, b_node,
                                                          cnt, h);
    edge_update<<<NEDGES / 256, 256, 0, stream>>>(feat, edge_feat, h, w_edge,
                                                  b_edge, src_idx, dst_idx, e);
}

// Round 2
// 1027.014 us; speedup vs baseline: 3.1969x; 3.1969x over previous
//
#include <hip/hip_runtime.h>

#define NNODES 50000
#define NEDGES 800000
#define NPAD   50176   // 196*256, padded bin count for the scan

// tanh(x) = 1 - 2/(exp(2x)+1); saturates cleanly, no NaN.
__device__ __forceinline__ float fast_tanh(float x) {
    float e = __expf(2.0f * x);
    return 1.0f - 2.0f * __builtin_amdgcn_rcpf(e + 1.0f);
}

// round-to-nearest-even f32->bf16, pack two into one uint
__device__ __forceinline__ unsigned pack_bf16x2(float a, float b) {
    unsigned ua = __float_as_uint(a), ub = __float_as_uint(b);
    ua = (ua + 0x7fffu + ((ua >> 16) & 1u)) >> 16;
    ub = (ub + 0x7fffu + ((ub >> 16) & 1u)) >> 16;
    return ua | (ub << 16);
}
__device__ __forceinline__ float bf16_lo(unsigned u) { return __uint_as_float(u << 16); }
__device__ __forceinline__ float bf16_hi(unsigned u) { return __uint_as_float(u & 0xffff0000u); }

// acc[j] += xk * wrow[j]; wrow is a wave-uniform LDS row (broadcast, conflict-free)
template <int NOUT>
__device__ __forceinline__ void fma_row(float (&acc)[NOUT], float xk,
                                        const float* __restrict__ wrow) {
#pragma unroll
    for (int j4 = 0; j4 < NOUT / 4; ++j4) {
        float4 w4 = ((const float4*)wrow)[j4];
        acc[j4 * 4 + 0] = fmaf(xk, w4.x, acc[j4 * 4 + 0]);
        acc[j4 * 4 + 1] = fmaf(xk, w4.y, acc[j4 * 4 + 1]);
        acc[j4 * 4 + 2] = fmaf(xk, w4.z, acc[j4 * 4 + 2]);
        acc[j4 * 4 + 3] = fmaf(xk, w4.w, acc[j4 * 4 + 3]);
    }
}

template <int NOUT>
__device__ __forceinline__ void fma_quad(float (&acc)[NOUT], float4 x4,
                                         const float* __restrict__ wbase) {
    fma_row<NOUT>(acc, x4.x, wbase + 0 * NOUT);
    fma_row<NOUT>(acc, x4.y, wbase + 1 * NOUT);
    fma_row<NOUT>(acc, x4.z, wbase + 2 * NOUT);
    fma_row<NOUT>(acc, x4.w, wbase + 3 * NOUT);
}

// ---------- K1: message MLP -> bf16 m rows + dst histogram ----------
__global__ __launch_bounds__(256) void msg_kernel(
    const float* __restrict__ feat, const float* __restrict__ edge_feat,
    const float* __restrict__ w_msg, const float* __restrict__ b_msg,
    const int* __restrict__ src_idx, const int* __restrict__ dst_idx,
    unsigned* __restrict__ m_out /* [NEDGES*32] packed bf16x2 */,
    int* __restrict__ cnt) {
    __shared__ __align__(16) float wl[96 * 64];
    __shared__ __align__(16) float bl[64];
    for (int i = threadIdx.x; i < 96 * 64; i += 256) wl[i] = w_msg[i];
    if (threadIdx.x < 64) bl[threadIdx.x] = b_msg[threadIdx.x];
    __syncthreads();

    const int t = blockIdx.x * 256 + threadIdx.x;  // 3125*256 == NEDGES exactly
    const int src = src_idx[t];
    const int dst = dst_idx[t];
    atomicAdd(&cnt[dst], 1);

    float acc[64];
#pragma unroll
    for (int j4 = 0; j4 < 16; ++j4) {
        float4 b4 = ((const float4*)bl)[j4];
        acc[j4 * 4 + 0] = b4.x; acc[j4 * 4 + 1] = b4.y;
        acc[j4 * 4 + 2] = b4.z; acc[j4 * 4 + 3] = b4.w;
    }

    const float4* fa = (const float4*)(feat + (size_t)src * 64);
    const float4* fe = (const float4*)(edge_feat + (size_t)t * 32);
#pragma unroll 1
    for (int kq = 0; kq < 16; ++kq)
        fma_quad<64>(acc, fa[kq], &wl[(kq * 4) * 64]);
#pragma unroll 1
    for (int kq = 0; kq < 8; ++kq)
        fma_quad<64>(acc, fe[kq], &wl[(64 + kq * 4) * 64]);

    uint4* mo = (uint4*)(m_out + (size_t)t * 32);
#pragma unroll 1
    for (int q = 0; q < 8; ++q) {
        uint4 o;
        o.x = pack_bf16x2(fast_tanh(acc[q * 8 + 0]), fast_tanh(acc[q * 8 + 1]));
        o.y = pack_bf16x2(fast_tanh(acc[q * 8 + 2]), fast_tanh(acc[q * 8 + 3]));
        o.z = pack_bf16x2(fast_tanh(acc[q * 8 + 4]), fast_tanh(acc[q * 8 + 5]));
        o.w = pack_bf16x2(fast_tanh(acc[q * 8 + 6]), fast_tanh(acc[q * 8 + 7]));
        mo[q] = o;
    }
}

// ---------- K2/K3/K4: exclusive scan of 50176 bins ----------
__global__ __launch_bounds__(256) void scan1(const int* __restrict__ cnt,
                                             int* __restrict__ off,
                                             int* __restrict__ btot) {
    __shared__ int s[256];
    const int tid = threadIdx.x;
    const int g = blockIdx.x * 256 + tid;
    const int own = cnt[g];
    s[tid] = own;
    __syncthreads();
    for (int o = 1; o < 256; o <<= 1) {
        int v = (tid >= o) ? s[tid - o] : 0;
        __syncthreads();
        s[tid] += v;
        __syncthreads();
    }
    off[g] = s[tid] - own;                    // block-local exclusive
    if (tid == 255) btot[blockIdx.x] = s[255];
}

__global__ __launch_bounds__(256) void scan2(int* __restrict__ btot) {
    __shared__ int s[256];
    const int tid = threadIdx.x;
    const int own = btot[tid];                // padded to 256 with zeros
    s[tid] = own;
    __syncthreads();
    for (int o = 1; o < 256; o <<= 1) {
        int v = (tid >= o) ? s[tid - o] : 0;
        __syncthreads();
        s[tid] += v;
        __syncthreads();
    }
    btot[tid] = s[tid] - own;                 // exclusive block offsets
}

__global__ __launch_bounds__(256) void scan3(int* __restrict__ off,
                                             const int* __restrict__ btot) {
    const int g = blockIdx.x * 256 + threadIdx.x;
    off[g] += btot[blockIdx.x];
}

// ---------- K5: build permutation (edges grouped by dst) ----------
// Uses off[] itself as the running cursor; afterwards off[d] == segment END.
__global__ __launch_bounds__(256) void perm_kernel(const int* __restrict__ dst_idx,
                                                   int* __restrict__ off,
                                                   int* __restrict__ perm) {
    const int t = blockIdx.x * 256 + threadIdx.x;
    const int d = dst_idx[t];
    const int pos = atomicAdd(&off[d], 1);
    perm[pos] = t;
}

// ---------- K6: segmented mean gather -> neigh (h region) ----------
// wave per node; lanes 0-31 and 32-63 each handle alternating edges,
// each lane covers 2 feature columns (one packed bf16x2 uint).
__global__ __launch_bounds__(256) void gather_kernel(
    const unsigned* __restrict__ m, const int* __restrict__ perm,
    const int* __restrict__ off /* segment ENDS after perm_kernel */,
    const int* __restrict__ cnt, float* __restrict__ neigh) {
    const int wave = threadIdx.x >> 6;
    const int lane = threadIdx.x & 63;
    const int n = blockIdx.x * 4 + wave;
    if (n >= NNODES) return;
    const int c = cnt[n];
    const int o = off[n] - c;  // segment start
    const int half = lane >> 5;
    const int p = lane & 31;

    float ax = 0.f, ay = 0.f;
    for (int e = half; e < c; e += 2) {
        const int row = perm[o + e];
        const unsigned u = m[(size_t)row * 32 + p];
        ax += bf16_lo(u);
        ay += bf16_hi(u);
    }
    ax += __shfl_xor(ax, 32);
    ay += __shfl_xor(ay, 32);
    if (half == 0) {
        const float inv = __builtin_amdgcn_rcpf((float)max(c, 1));
        float2 o2 = {ax * inv, ay * inv};
        ((float2*)(neigh + (size_t)n * 64))[p] = o2;
    }
}

// ---------- K7: node MLP ----------
// h = tanh([neigh, feat] @ w_node + b_node); neigh pre-divided, in h region.
__global__ __launch_bounds__(256) void node_update(
    const float* __restrict__ feat,
    const float* __restrict__ w_node, const float* __restrict__ b_node,
    float* __restrict__ h) {
    __shared__ __align__(16) float wl[128 * 64];
    __shared__ __align__(16) float bl[64];
    for (int i = threadIdx.x; i < 128 * 64; i += 256) wl[i] = w_node[i];
    if (threadIdx.x < 64) bl[threadIdx.x] = b_node[threadIdx.x];
    __syncthreads();

    const int t = blockIdx.x * 256 + threadIdx.x;
    if (t >= NNODES) return;

    float acc[64];
#pragma unroll
    for (int j4 = 0; j4 < 16; ++j4) {
        float4 b4 = ((const float4*)bl)[j4];
        acc[j4 * 4 + 0] = b4.x; acc[j4 * 4 + 1] = b4.y;
        acc[j4 * 4 + 2] = b4.z; acc[j4 * 4 + 3] = b4.w;
    }

    const float4* sv = (const float4*)(h + (size_t)t * 64);
    const float4* fv = (const float4*)(feat + (size_t)t * 64);
#pragma unroll 1
    for (int kq = 0; kq < 16; ++kq)
        fma_quad<64>(acc, sv[kq], &wl[(kq * 4) * 64]);
#pragma unroll 1
    for (int kq = 0; kq < 16; ++kq)
        fma_quad<64>(acc, fv[kq], &wl[(64 + kq * 4) * 64]);

    float4* ho = (float4*)(h + (size_t)t * 64);
#pragma unroll 1
    for (int j4 = 0; j4 < 16; ++j4) {
        float4 o;
        o.x = fast_tanh(acc[j4 * 4 + 0]);
        o.y = fast_tanh(acc[j4 * 4 + 1]);
        o.z = fast_tanh(acc[j4 * 4 + 2]);
        o.w = fast_tanh(acc[j4 * 4 + 3]);
        ho[j4] = o;
    }
}

// ---------- K8: edge MLP ----------
__global__ __launch_bounds__(256) void edge_update(
    const float* __restrict__ feat, const float* __restrict__ edge_feat,
    const float* __restrict__ h,
    const float* __restrict__ w_edge, const float* __restrict__ b_edge,
    const int* __restrict__ src_idx, const int* __restrict__ dst_idx,
    float* __restrict__ e_out) {
    __shared__ __align__(16) float wl[160 * 32];
    __shared__ __align__(16) float bl[32];
    for (int i = threadIdx.x; i < 160 * 32; i += 256) wl[i] = w_edge[i];
    if (threadIdx.x < 32) bl[threadIdx.x] = b_edge[threadIdx.x];
    __syncthreads();

    const int t = blockIdx.x * 256 + threadIdx.x;
    const int src = src_idx[t];
    const int dst = dst_idx[t];

    float acc[32];
#pragma unroll
    for (int j4 = 0; j4 < 8; ++j4) {
        float4 b4 = ((const float4*)bl)[j4];
        acc[j4 * 4 + 0] = b4.x; acc[j4 * 4 + 1] = b4.y;
        acc[j4 * 4 + 2] = b4.z; acc[j4 * 4 + 3] = b4.w;
    }

    const float4* fa = (const float4*)(feat + (size_t)src * 64);
    const float4* fh = (const float4*)(h + (size_t)dst * 64);
    const float4* fe = (const float4*)(edge_feat + (size_t)t * 32);
#pragma unroll 1
    for (int kq = 0; kq < 16; ++kq)
        fma_quad<32>(acc, fa[kq], &wl[(kq * 4) * 32]);
#pragma unroll 1
    for (int kq = 0; kq < 16; ++kq)
        fma_quad<32>(acc, fh[kq], &wl[(64 + kq * 4) * 32]);
#pragma unroll 1
    for (int kq = 0; kq < 8; ++kq)
        fma_quad<32>(acc, fe[kq], &wl[(128 + kq * 4) * 32]);

    float4* eo = (float4*)(e_out + (size_t)t * 32);
#pragma unroll 1
    for (int j4 = 0; j4 < 8; ++j4) {
        float4 o;
        o.x = fast_tanh(acc[j4 * 4 + 0]);
        o.y = fast_tanh(acc[j4 * 4 + 1]);
        o.z = fast_tanh(acc[j4 * 4 + 2]);
        o.w = fast_tanh(acc[j4 * 4 + 3]);
        eo[j4] = o;
    }
}

extern "C" void kernel_launch(void* const* d_in, const int* in_sizes, int n_in,
                              void* d_out, int out_size, void* d_ws, size_t ws_size,
                              hipStream_t stream) {
    const float* feat      = (const float*)d_in[0];
    const float* edge_feat = (const float*)d_in[1];
    const float* w_msg     = (const float*)d_in[2];
    const float* b_msg     = (const float*)d_in[3];
    const float* w_node    = (const float*)d_in[4];
    const float* b_node    = (const float*)d_in[5];
    const float* w_edge    = (const float*)d_in[6];
    const float* b_edge    = (const float*)d_in[7];
    const int*   src_idx   = (const int*)d_in[8];
    const int*   dst_idx   = (const int*)d_in[9];

    float* h = (float*)d_out;                            // [50000,64]
    float* e = (float*)d_out + (size_t)NNODES * 64;      // [800000,32]
    // bf16 message matrix lives in the (not-yet-written) e region:
    // 800000*64*2 B == 800000*32*4 B exactly.
    unsigned* m = (unsigned*)e;

    int* cnt  = (int*)d_ws;          // [NPAD]
    int* off  = cnt + NPAD;          // [NPAD]
    int* btot = off + NPAD;          // [256]
    int* perm = btot + 256;          // [NEDGES]

    // zero cnt + btot (off is fully written by scan1)
    hipMemsetAsync(cnt, 0, NPAD * sizeof(int), stream);
    hipMemsetAsync(btot, 0, 256 * sizeof(int), stream);

    msg_kernel<<<NEDGES / 256, 256, 0, stream>>>(feat, edge_feat, w_msg, b_msg,
                                                 src_idx, dst_idx, m, cnt);
    scan1<<<NPAD / 256, 256, 0, stream>>>(cnt, off, btot);
    scan2<<<1, 256, 0, stream>>>(btot);
    scan3<<<NPAD / 256, 256, 0, stream>>>(off, btot);
    perm_kernel<<<NEDGES / 256, 256, 0, stream>>>(dst_idx, off, perm);
    gather_kernel<<<(NNODES + 3) / 4, 256, 0, stream>>>(m, perm, off, cnt, h);
    node_update<<<(NNODES + 255) / 256, 256, 0, stream>>>(feat, w_node, b_node, h);
    edge_update<<<NEDGES / 256, 256, 0, stream>>>(feat, edge_feat, h, w_edge,
                                                  b_edge, src_idx, dst_idx, e);
}

// Round 3
// 484.248 us; speedup vs baseline: 6.7801x; 2.1208x over previous
//
#include <hip/hip_runtime.h>

#define NNODES 50000
#define NEDGES 800000
#define NPAD   50176   // 196*256, padded bin count for the scan

typedef __attribute__((ext_vector_type(8))) short bf16x8;   // 8 bf16 = 4 VGPRs
typedef __attribute__((ext_vector_type(4))) float f32x4;

union ABu { bf16x8 v; uint4 u; };

// tanh(x) = 1 - 2/(exp(2x)+1); saturates cleanly, no NaN.
__device__ __forceinline__ float fast_tanh(float x) {
    float e = __expf(2.0f * x);
    return 1.0f - 2.0f * __builtin_amdgcn_rcpf(e + 1.0f);
}

// RNE pack two f32 -> bf16x2
__device__ __forceinline__ unsigned pk_rne(float x, float y) {
    unsigned a = __float_as_uint(x), b = __float_as_uint(y);
    a = (a + 0x7fffu + ((a >> 16) & 1u)) >> 16;
    b = (b + 0x7fffu + ((b >> 16) & 1u)) >> 16;
    return a | (b << 16);
}
// truncating pack (1 v_perm): dst = {a[31:16], b[31:16]}
__device__ __forceinline__ unsigned pk_tr(float a, float b) {
    return __builtin_amdgcn_perm(__float_as_uint(b), __float_as_uint(a), 0x07060302);
}
__device__ __forceinline__ float bf16_lo(unsigned u) { return __uint_as_float(u << 16); }
__device__ __forceinline__ float bf16_hi(unsigned u) { return __uint_as_float(u & 0xffff0000u); }

// A-fragment (lane holds A[m=lane&15][k=quad*8+j]) from 8 consecutive f32
__device__ __forceinline__ ABu make_afrag(const float* p) {
    float4 a = ((const float4*)p)[0];
    float4 b = ((const float4*)p)[1];
    ABu r;
    r.u.x = pk_tr(a.x, a.y); r.u.y = pk_tr(a.z, a.w);
    r.u.z = pk_tr(b.x, b.y); r.u.w = pk_tr(b.z, b.w);
    return r;
}

// B-fragment (lane holds B[k=quad*8+j][n=lane&15]) from LDS, row stride LDW
template <int LDW>
__device__ __forceinline__ ABu make_bfrag(const float* wp) {
    ABu r;
    r.u.x = pk_rne(wp[0 * LDW], wp[1 * LDW]);
    r.u.y = pk_rne(wp[2 * LDW], wp[3 * LDW]);
    r.u.z = pk_rne(wp[4 * LDW], wp[5 * LDW]);
    r.u.w = pk_rne(wp[6 * LDW], wp[7 * LDW]);
    return r;
}

#define MFMA(a, b, c) __builtin_amdgcn_mfma_f32_16x16x32_bf16((a).v, (b).v, (c), 0, 0, 0)

// ---------- K1: message MLP (MFMA) -> swizzled bf16 m rows + dst histogram ----------
// m storage (uint index s in [0,32) per edge): s = col*2 + w;
//   w=0 -> logical cols (col, col+16), w=1 -> (col+32, col+48)
__global__ __launch_bounds__(256) void msg_kernel(
    const float* __restrict__ feat, const float* __restrict__ edge_feat,
    const float* __restrict__ w_msg, const float* __restrict__ b_msg,
    const int* __restrict__ src_idx, const int* __restrict__ dst_idx,
    unsigned* __restrict__ m_out, int* __restrict__ cnt) {
    __shared__ __align__(16) float wl[96 * 64];
    for (int i = threadIdx.x; i < 96 * 64; i += 256) wl[i] = w_msg[i];
    __syncthreads();

    const int lane = threadIdx.x & 63, wave = threadIdx.x >> 6;
    const int col = lane & 15, quad = lane >> 4;

    ABu bf[3][4];
#pragma unroll
    for (int kc = 0; kc < 3; ++kc)
#pragma unroll
        for (int nt = 0; nt < 4; ++nt)
            bf[kc][nt] = make_bfrag<64>(&wl[(kc * 32 + quad * 8) * 64 + nt * 16 + col]);

    float bias[4];
#pragma unroll
    for (int nt = 0; nt < 4; ++nt) bias[nt] = b_msg[nt * 16 + col];

    const int e0 = (blockIdx.x * 4 + wave) * 16;
    const int e = e0 + col;
    const int src = src_idx[e];
    if (quad == 0) atomicAdd(&cnt[dst_idx[e]], 1);

    ABu a0 = make_afrag(feat + (size_t)src * 64 + quad * 8);
    ABu a1 = make_afrag(feat + (size_t)src * 64 + 32 + quad * 8);
    ABu a2 = make_afrag(edge_feat + (size_t)e * 32 + quad * 8);

    f32x4 acc[4];
#pragma unroll
    for (int nt = 0; nt < 4; ++nt)
        acc[nt] = (f32x4){bias[nt], bias[nt], bias[nt], bias[nt]};
#pragma unroll
    for (int nt = 0; nt < 4; ++nt) {
        acc[nt] = MFMA(a0, bf[0][nt], acc[nt]);
        acc[nt] = MFMA(a1, bf[1][nt], acc[nt]);
        acc[nt] = MFMA(a2, bf[2][nt], acc[nt]);
    }
#pragma unroll
    for (int i = 0; i < 4; ++i) {
        const int er = e0 + quad * 4 + i;
        uint2 o;
        o.x = pk_rne(fast_tanh(acc[0][i]), fast_tanh(acc[1][i]));
        o.y = pk_rne(fast_tanh(acc[2][i]), fast_tanh(acc[3][i]));
        *(uint2*)(m_out + (size_t)er * 32 + col * 2) = o;  // 128B/quad contiguous
    }
}

// ---------- K2/K3/K4: exclusive scan of 50176 bins ----------
__global__ __launch_bounds__(256) void scan1(const int* __restrict__ cnt,
                                             int* __restrict__ off,
                                             int* __restrict__ btot) {
    __shared__ int s[256];
    const int tid = threadIdx.x;
    const int g = blockIdx.x * 256 + tid;
    const int own = cnt[g];
    s[tid] = own;
    __syncthreads();
    for (int o = 1; o < 256; o <<= 1) {
        int v = (tid >= o) ? s[tid - o] : 0;
        __syncthreads();
        s[tid] += v;
        __syncthreads();
    }
    off[g] = s[tid] - own;
    if (tid == 255) btot[blockIdx.x] = s[255];
}

__global__ __launch_bounds__(256) void scan2(int* __restrict__ btot) {
    __shared__ int s[256];
    const int tid = threadIdx.x;
    const int own = btot[tid];
    s[tid] = own;
    __syncthreads();
    for (int o = 1; o < 256; o <<= 1) {
        int v = (tid >= o) ? s[tid - o] : 0;
        __syncthreads();
        s[tid] += v;
        __syncthreads();
    }
    btot[tid] = s[tid] - own;
}

__global__ __launch_bounds__(256) void scan3(int* __restrict__ off,
                                             const int* __restrict__ btot) {
    const int g = blockIdx.x * 256 + threadIdx.x;
    off[g] += btot[blockIdx.x];
}

// ---------- K5: build permutation (edges grouped by dst) ----------
__global__ __launch_bounds__(256) void perm_kernel(const int* __restrict__ dst_idx,
                                                   int* __restrict__ off,
                                                   int* __restrict__ perm) {
    const int t = blockIdx.x * 256 + threadIdx.x;
    const int d = dst_idx[t];
    const int pos = atomicAdd(&off[d], 1);
    perm[pos] = t;
}

// ---------- K6: segmented mean gather -> neigh (h region, swizzled storage) ----------
__global__ __launch_bounds__(256) void gather_kernel(
    const unsigned* __restrict__ m, const int* __restrict__ perm,
    const int* __restrict__ off /* segment ENDS */, const int* __restrict__ cnt,
    float* __restrict__ neigh) {
    const int wave = threadIdx.x >> 6;
    const int lane = threadIdx.x & 63;
    const int n = blockIdx.x * 4 + wave;
    if (n >= NNODES) return;
    const int c = cnt[n];
    const int o = off[n] - c;
    const int half = lane >> 5;
    const int p = lane & 31;

    float ax = 0.f, ay = 0.f;
    for (int e = half; e < c; e += 2) {
        const int row = perm[o + e];
        const unsigned u = m[(size_t)row * 32 + p];
        ax += bf16_lo(u);
        ay += bf16_hi(u);
    }
    ax += __shfl_xor(ax, 32);
    ay += __shfl_xor(ay, 32);
    if (half == 0) {
        const float inv = __builtin_amdgcn_rcpf((float)max(c, 1));
        float2 o2 = {ax * inv, ay * inv};
        ((float2*)(neigh + (size_t)n * 64))[p] = o2;  // storage order, unswizzled in K7
    }
}

// storage k -> logical w_node row (undo the m/neigh swizzle) for k<64
__device__ __forceinline__ int mapk(int ks) {
    return ks < 64 ? ((ks >> 2) + ((ks >> 1) & 1) * 32 + (ks & 1) * 16) : ks;
}

// ---------- K7: node MLP (MFMA) ----------
__global__ __launch_bounds__(256) void node_update(
    const float* __restrict__ feat,
    const float* __restrict__ w_node, const float* __restrict__ b_node,
    float* __restrict__ h) {
    __shared__ __align__(16) float wl[128 * 64];
    for (int i = threadIdx.x; i < 128 * 64; i += 256) wl[i] = w_node[i];
    __syncthreads();

    const int lane = threadIdx.x & 63, wave = threadIdx.x >> 6;
    const int col = lane & 15, quad = lane >> 4;
    const int n0 = (blockIdx.x * 4 + wave) * 16;
    if (n0 >= NNODES) return;  // NNODES = 3125*16, tiles are exact

    ABu bf[4][4];
#pragma unroll
    for (int kc = 0; kc < 4; ++kc)
#pragma unroll
        for (int nt = 0; nt < 4; ++nt) {
            unsigned p[4];
#pragma unroll
            for (int jj = 0; jj < 4; ++jj) {
                const int k0 = kc * 32 + quad * 8 + jj * 2;
                p[jj] = pk_rne(wl[mapk(k0) * 64 + nt * 16 + col],
                               wl[mapk(k0 + 1) * 64 + nt * 16 + col]);
            }
            bf[kc][nt].u = (uint4){p[0], p[1], p[2], p[3]};
        }

    float bias[4];
#pragma unroll
    for (int nt = 0; nt < 4; ++nt) bias[nt] = b_node[nt * 16 + col];

    const int n = n0 + col;
    ABu a0 = make_afrag(h + (size_t)n * 64 + quad * 8);        // neigh (storage order)
    ABu a1 = make_afrag(h + (size_t)n * 64 + 32 + quad * 8);
    ABu a2 = make_afrag(feat + (size_t)n * 64 + quad * 8);
    ABu a3 = make_afrag(feat + (size_t)n * 64 + 32 + quad * 8);

    f32x4 acc[4];
#pragma unroll
    for (int nt = 0; nt < 4; ++nt)
        acc[nt] = (f32x4){bias[nt], bias[nt], bias[nt], bias[nt]};
#pragma unroll
    for (int nt = 0; nt < 4; ++nt) {
        acc[nt] = MFMA(a0, bf[0][nt], acc[nt]);
        acc[nt] = MFMA(a1, bf[1][nt], acc[nt]);
        acc[nt] = MFMA(a2, bf[2][nt], acc[nt]);
        acc[nt] = MFMA(a3, bf[3][nt], acc[nt]);
    }
#pragma unroll
    for (int i = 0; i < 4; ++i) {
        const int nr = n0 + quad * 4 + i;
#pragma unroll
        for (int nt = 0; nt < 4; ++nt)
            h[(size_t)nr * 64 + nt * 16 + col] = fast_tanh(acc[nt][i]);
    }
}

// ---------- K8: edge MLP (MFMA) ----------
__global__ __launch_bounds__(256) void edge_update(
    const float* __restrict__ feat, const float* __restrict__ edge_feat,
    const float* __restrict__ h,
    const float* __restrict__ w_edge, const float* __restrict__ b_edge,
    const int* __restrict__ src_idx, const int* __restrict__ dst_idx,
    float* __restrict__ e_out) {
    __shared__ __align__(16) float wl[160 * 32];
    for (int i = threadIdx.x; i < 160 * 32; i += 256) wl[i] = w_edge[i];
    __syncthreads();

    const int lane = threadIdx.x & 63, wave = threadIdx.x >> 6;
    const int col = lane & 15, quad = lane >> 4;

    ABu bf[5][2];
#pragma unroll
    for (int kc = 0; kc < 5; ++kc)
#pragma unroll
        for (int nt = 0; nt < 2; ++nt)
            bf[kc][nt] = make_bfrag<32>(&wl[(kc * 32 + quad * 8) * 32 + nt * 16 + col]);

    float bias[2];
#pragma unroll
    for (int nt = 0; nt < 2; ++nt) bias[nt] = b_edge[nt * 16 + col];

    const int e0 = (blockIdx.x * 4 + wave) * 16;
    const int e = e0 + col;
    const int src = src_idx[e];
    const int dst = dst_idx[e];

    ABu a0 = make_afrag(feat + (size_t)src * 64 + quad * 8);
    ABu a1 = make_afrag(feat + (size_t)src * 64 + 32 + quad * 8);
    ABu a2 = make_afrag(h + (size_t)dst * 64 + quad * 8);
    ABu a3 = make_afrag(h + (size_t)dst * 64 + 32 + quad * 8);
    ABu a4 = make_afrag(edge_feat + (size_t)e * 32 + quad * 8);

    f32x4 acc[2];
#pragma unroll
    for (int nt = 0; nt < 2; ++nt)
        acc[nt] = (f32x4){bias[nt], bias[nt], bias[nt], bias[nt]};
#pragma unroll
    for (int nt = 0; nt < 2; ++nt) {
        acc[nt] = MFMA(a0, bf[0][nt], acc[nt]);
        acc[nt] = MFMA(a1, bf[1][nt], acc[nt]);
        acc[nt] = MFMA(a2, bf[2][nt], acc[nt]);
        acc[nt] = MFMA(a3, bf[3][nt], acc[nt]);
        acc[nt] = MFMA(a4, bf[4][nt], acc[nt]);
    }
#pragma unroll
    for (int i = 0; i < 4; ++i) {
        const int er = e0 + quad * 4 + i;
        e_out[(size_t)er * 32 + col] = fast_tanh(acc[0][i]);
        e_out[(size_t)er * 32 + 16 + col] = fast_tanh(acc[1][i]);
    }
}

extern "C" void kernel_launch(void* const* d_in, const int* in_sizes, int n_in,
                              void* d_out, int out_size, void* d_ws, size_t ws_size,
                              hipStream_t stream) {
    const float* feat      = (const float*)d_in[0];
    const float* edge_feat = (const float*)d_in[1];
    const float* w_msg     = (const float*)d_in[2];
    const float* b_msg     = (const float*)d_in[3];
    const float* w_node    = (const float*)d_in[4];
    const float* b_node    = (const float*)d_in[5];
    const float* w_edge    = (const float*)d_in[6];
    const float* b_edge    = (const float*)d_in[7];
    const int*   src_idx   = (const int*)d_in[8];
    const int*   dst_idx   = (const int*)d_in[9];

    float* h = (float*)d_out;                            // [50000,64]
    float* e = (float*)d_out + (size_t)NNODES * 64;      // [800000,32]
    unsigned* m = (unsigned*)e;  // bf16 m matrix in the not-yet-written e region

    int* cnt  = (int*)d_ws;          // [NPAD]
    int* off  = cnt + NPAD;          // [NPAD]
    int* btot = off + NPAD;          // [256]
    int* perm = btot + 256;          // [NEDGES]

    hipMemsetAsync(cnt, 0, NPAD * sizeof(int), stream);
    hipMemsetAsync(btot, 0, 256 * sizeof(int), stream);

    msg_kernel<<<NEDGES / 16 / 4, 256, 0, stream>>>(feat, edge_feat, w_msg, b_msg,
                                                    src_idx, dst_idx, m, cnt);
    scan1<<<NPAD / 256, 256, 0, stream>>>(cnt, off, btot);
    scan2<<<1, 256, 0, stream>>>(btot);
    scan3<<<NPAD / 256, 256, 0, stream>>>(off, btot);
    perm_kernel<<<NEDGES / 256, 256, 0, stream>>>(dst_idx, off, perm);
    gather_kernel<<<(NNODES + 3) / 4, 256, 0, stream>>>(m, perm, off, cnt, h);
    node_update<<<(NNODES / 16 + 3) / 4, 256, 0, stream>>>(feat, w_node, b_node, h);
    edge_update<<<NEDGES / 16 / 4, 256, 0, stream>>>(feat, edge_feat, h, w_edge,
                                                     b_edge, src_idx, dst_idx, e);
}